// Round 1
// baseline (444.032 us; speedup 1.0000x reference)
//
#include <hip/hip_runtime.h>
#include <hip/hip_bf16.h>

#define AS1 __attribute__((address_space(1)))
#define AS3 __attribute__((address_space(3)))

typedef __bf16 bf16x8 __attribute__((ext_vector_type(8)));
typedef float f32x4 __attribute__((ext_vector_type(4)));

#define GLOAD_LDS16(gptr, lptr) \
  __builtin_amdgcn_global_load_lds((AS1 void*)(gptr), (AS3 void*)(lptr), 16, 0, 0)

// ---------------- constants ----------------
#define M_W   4096   // rows of W (output features)
#define K_DIM 4096   // inner dim
#define M_X   8192   // rows of x (batch*seq)
#define NT_T  65536
#define TSTEPS 128

__device__ __forceinline__ unsigned short f2bf(float f) {
  unsigned int u = __float_as_uint(f);
  unsigned int r = (u + 0x7FFFu + ((u >> 16) & 1u)) >> 16;
  return (unsigned short)r;
}

// ---------------- x fp32 -> bf16 (8 elems/thread) ----------------
__global__ void cvt_kernel(const float* __restrict__ x, unsigned short* __restrict__ xb) {
  int idx = blockIdx.x * blockDim.x + threadIdx.x;
  const float4* p = reinterpret_cast<const float4*>(x) + (size_t)idx * 2;
  float4 u = p[0];
  float4 v = p[1];
  uint4 o;
  o.x = (unsigned)f2bf(u.x) | ((unsigned)f2bf(u.y) << 16);
  o.y = (unsigned)f2bf(u.z) | ((unsigned)f2bf(u.w) << 16);
  o.z = (unsigned)f2bf(v.x) | ((unsigned)f2bf(v.y) << 16);
  o.w = (unsigned)f2bf(v.z) | ((unsigned)f2bf(v.w) << 16);
  reinterpret_cast<uint4*>(xb)[idx] = o;
}

// ---------------- trellis decode -> W bf16 [4096][4096] row-major ----------------
__global__ void decode_kernel(const int* __restrict__ trellis,
                              const float* __restrict__ tlut,
                              unsigned short* __restrict__ W) {
  int idx = blockIdx.x * blockDim.x + threadIdx.x;   // t*128 + s
  int t = idx >> 7;
  int s = idx & 127;
  const unsigned int* tr = reinterpret_cast<const unsigned int*>(trellis) + t * 32;
  int w0  = s >> 2;
  int off = (s & 3) * 4;
  unsigned int a = tr[w0] & 0xFFFFu;
  unsigned int state;
  if (off == 0) {
    state = a;
  } else {
    unsigned int b = tr[(w0 + 1) & 31] & 0xFFFFu;
    state = ((a << off) | (b >> (16 - off))) & 0xFFFFu;
  }
  unsigned int code = state & 0x1FFu;
  float2 v = reinterpret_cast<const float2*>(tlut)[code];
  // tile t -> (i, j); element flat = 2s -> (r, c)
  int i = t >> 8;          // M/16 index
  int j = t & 255;         // K/16 index
  int flat = s * 2;
  int r = flat >> 4;
  int c = flat & 15;
  unsigned int packed = (unsigned)f2bf(v.x) | ((unsigned)f2bf(v.y) << 16);
  size_t o = (size_t)(i * 16 + r) * K_DIM + (j * 16 + c);
  *reinterpret_cast<unsigned int*>(W + o) = packed;
}

// ---------------- bf16 GEMM: y[M_X, M_W] = xb[M_X,K] * W[M_W,K]^T ----------------
// m97 structure: 128x128 tile, BK=32, 4 waves, global_load_lds(16B), 16x16x32 MFMA.
__global__ __launch_bounds__(256) void gemm_kernel(const unsigned short* __restrict__ xb,
                                                   const unsigned short* __restrict__ W,
                                                   float* __restrict__ y) {
  __shared__ unsigned short sA[128 * 32];
  __shared__ unsigned short sB[128 * 32];

  // XCD-aware bijective swizzle: 2048 blocks, 8 XCDs, 256 per XCD
  int bid = blockIdx.x;
  int swz = (bid & 7) * 256 + (bid >> 3);
  int row_t = swz >> 5;          // 0..63 (M_X/128)
  int col_t = swz & 31;          // 0..31 (M_W/128)
  int brow = row_t * 128;
  int bcol = col_t * 128;

  int tid  = threadIdx.x;
  int lane = tid & 63;
  int wid  = tid >> 6;
  int wr = wid >> 1;             // 0..1
  int wc = wid & 1;              // 0..1

  // staging source addresses (element offsets)
  int arow  = tid >> 2;          // 0..63
  int acol8 = (tid & 3) * 8;
  const unsigned short* gA = xb + (size_t)(brow + arow) * K_DIM + acol8;
  const unsigned short* gB = W  + (size_t)(bcol + arow) * K_DIM + acol8;
  unsigned short* lA = sA + tid * 8;
  unsigned short* lB = sB + tid * 8;

  f32x4 acc[4][4];
  #pragma unroll
  for (int m = 0; m < 4; ++m)
    #pragma unroll
    for (int n = 0; n < 4; ++n)
      acc[m][n] = (f32x4){0.f, 0.f, 0.f, 0.f};

  int lr = lane >> 4;            // 0..3
  int lc = lane & 15;
  // fragment LDS indices (in bf16x8 units): row*4 + (lane>>4)
  const bf16x8* fA = reinterpret_cast<const bf16x8*>(sA);
  const bf16x8* fB = reinterpret_cast<const bf16x8*>(sB);
  int aBase = (wr * 64 + lc) * 4 + lr;   // + m*64
  int bBase = (wc * 64 + lc) * 4 + lr;   // + n*64

  for (int k0 = 0; k0 < K_DIM; k0 += 32) {
    GLOAD_LDS16(gA + k0,                 lA);
    GLOAD_LDS16(gA + (size_t)64 * K_DIM + k0, lA + 2048);
    GLOAD_LDS16(gB + k0,                 lB);
    GLOAD_LDS16(gB + (size_t)64 * K_DIM + k0, lB + 2048);
    __syncthreads();

    bf16x8 af[4], bf[4];
    #pragma unroll
    for (int m = 0; m < 4; ++m) af[m] = fA[aBase + m * 64];
    #pragma unroll
    for (int n = 0; n < 4; ++n) bf[n] = fB[bBase + n * 64];

    #pragma unroll
    for (int m = 0; m < 4; ++m)
      #pragma unroll
      for (int n = 0; n < 4; ++n)
        acc[m][n] = __builtin_amdgcn_mfma_f32_16x16x32_bf16(af[m], bf[n], acc[m][n], 0, 0, 0);

    __syncthreads();
  }

  // epilogue: C/D layout col=lane&15, row=(lane>>4)*4+j
  #pragma unroll
  for (int m = 0; m < 4; ++m) {
    #pragma unroll
    for (int n = 0; n < 4; ++n) {
      int col = bcol + wc * 64 + n * 16 + lc;
      int rowb = brow + wr * 64 + m * 16 + lr * 4;
      #pragma unroll
      for (int j = 0; j < 4; ++j) {
        y[(size_t)(rowb + j) * M_W + col] = acc[m][n][j];
      }
    }
  }
}

extern "C" void kernel_launch(void* const* d_in, const int* in_sizes, int n_in,
                              void* d_out, int out_size, void* d_ws, size_t ws_size,
                              hipStream_t stream) {
  const float* inp     = (const float*)d_in[0];
  const int*   trellis = (const int*)d_in[1];
  const float* tlut    = (const float*)d_in[2];
  float* y = (float*)d_out;

  unsigned short* xb = (unsigned short*)d_ws;                       // 8192*4096*2 = 64 MiB
  unsigned short* Wd = (unsigned short*)((char*)d_ws + (size_t)M_X * K_DIM * 2);  // 32 MiB

  // 1) convert x to bf16
  {
    int total = M_X * K_DIM / 8;      // 4194304 threads
    cvt_kernel<<<total / 256, 256, 0, stream>>>(inp, xb);
  }
  // 2) decode W
  {
    int total = NT_T * TSTEPS;        // 8388608 threads
    decode_kernel<<<total / 256, 256, 0, stream>>>(trellis, tlut, Wd);
  }
  // 3) GEMM
  {
    dim3 grid((M_X / 128) * (M_W / 128));   // 2048
    gemm_kernel<<<grid, 256, 0, stream>>>(xb, Wd, y);
  }
}

// Round 2
// 281.802 us; speedup vs baseline: 1.5757x; 1.5757x over previous
//
#include <hip/hip_runtime.h>
#include <hip/hip_bf16.h>

#define AS1 __attribute__((address_space(1)))
#define AS3 __attribute__((address_space(3)))

typedef __bf16 bf16x8 __attribute__((ext_vector_type(8)));
typedef float f32x4 __attribute__((ext_vector_type(4)));

#define GLOAD_LDS16(gptr, lptr) \
  __builtin_amdgcn_global_load_lds((AS1 void*)(gptr), (AS3 void*)(lptr), 16, 0, 0)

#define M_W   4096   // output features (rows of W)
#define K_DIM 4096
#define M_X   8192   // batch*seq
#define NT_T  65536
#define TSTEPS 128
#define NKT   (K_DIM/64)   // 64 K-tiles of 64

#define BAR()        asm volatile("s_barrier" ::: "memory")
#define WAIT_LGKM0() asm volatile("s_waitcnt lgkmcnt(0)" ::: "memory")
#define WAIT_VM4()   asm volatile("s_waitcnt vmcnt(4)" ::: "memory")
#define WAIT_VM0()   asm volatile("s_waitcnt vmcnt(0)" ::: "memory")

__device__ __forceinline__ unsigned short f2bf(float f) {
  unsigned int u = __float_as_uint(f);
  unsigned int r = (u + 0x7FFFu + ((u >> 16) & 1u)) >> 16;
  return (unsigned short)r;
}

// ---------------- x fp32 -> bf16 ----------------
__global__ void cvt_kernel(const float* __restrict__ x, unsigned short* __restrict__ xb) {
  int idx = blockIdx.x * blockDim.x + threadIdx.x;
  const float4* p = reinterpret_cast<const float4*>(x) + (size_t)idx * 2;
  float4 u = p[0];
  float4 v = p[1];
  uint4 o;
  o.x = (unsigned)f2bf(u.x) | ((unsigned)f2bf(u.y) << 16);
  o.y = (unsigned)f2bf(u.z) | ((unsigned)f2bf(u.w) << 16);
  o.z = (unsigned)f2bf(v.x) | ((unsigned)f2bf(v.y) << 16);
  o.w = (unsigned)f2bf(v.z) | ((unsigned)f2bf(v.w) << 16);
  reinterpret_cast<uint4*>(xb)[idx] = o;
}

// ---------------- trellis decode -> W bf16 [4096][4096] ----------------
__global__ void decode_kernel(const int* __restrict__ trellis,
                              const float* __restrict__ tlut,
                              unsigned short* __restrict__ W) {
  int idx = blockIdx.x * blockDim.x + threadIdx.x;   // t*128 + s
  int t = idx >> 7;
  int s = idx & 127;
  const unsigned int* tr = reinterpret_cast<const unsigned int*>(trellis) + t * 32;
  int w0  = s >> 2;
  int off = (s & 3) * 4;
  unsigned int a = tr[w0] & 0xFFFFu;
  unsigned int state;
  if (off == 0) {
    state = a;
  } else {
    unsigned int b = tr[(w0 + 1) & 31] & 0xFFFFu;
    state = ((a << off) | (b >> (16 - off))) & 0xFFFFu;
  }
  unsigned int code = state & 0x1FFu;
  float2 v = reinterpret_cast<const float2*>(tlut)[code];
  int i = t >> 8;
  int j = t & 255;
  int flat = s * 2;
  int r = flat >> 4;
  int c = flat & 15;
  unsigned int packed = (unsigned)f2bf(v.x) | ((unsigned)f2bf(v.y) << 16);
  size_t o = (size_t)(i * 16 + r) * K_DIM + (j * 16 + c);
  *reinterpret_cast<unsigned int*>(W + o) = packed;
}

// ---------------- 256x256 8-phase bf16 GEMM ----------------
// y[8192,4096] = xb[8192,4096] * W[4096,4096]^T
// LDS slots (bytes): A(buf,half) = (buf*2+half)*16384 ; B(buf,half) = 65536 + (buf*2+half)*16384
// Half-tile layout: 128 local rows x 64 cols bf16, row stride 128 B, 16B chunks XOR-swizzled:
//   LDS(la, c16) holds global chunk (c16 ^ (la&7)) of row(la).

template<int BUF, int MH>
__device__ __forceinline__ void lda(const char* ldsc, const int* aRow, const int* kOff,
                                    bf16x8 af[4][2]) {
  const char* base = ldsc + (BUF * 2 + MH) * 16384;
  #pragma unroll
  for (int fm = 0; fm < 4; ++fm)
    #pragma unroll
    for (int kh = 0; kh < 2; ++kh)
      af[fm][kh] = *(const bf16x8*)(base + aRow[fm] + kOff[kh]);
}

template<int BUF, int NH>
__device__ __forceinline__ void ldb(const char* ldsc, const int* bRow, const int* kOff,
                                    bf16x8 bq[2][2]) {
  const char* base = ldsc + 65536 + (BUF * 2 + NH) * 16384;
  #pragma unroll
  for (int fn = 0; fn < 2; ++fn)
    #pragma unroll
    for (int kh = 0; kh < 2; ++kh)
      bq[fn][kh] = *(const bf16x8*)(base + bRow[fn] + kOff[kh]);
}

template<int MH, int NH>
__device__ __forceinline__ void mm(bf16x8 af[4][2], bf16x8 bq[2][2], f32x4 acc[8][4]) {
  __builtin_amdgcn_s_setprio(1);
  #pragma unroll
  for (int fm = 0; fm < 4; ++fm)
    #pragma unroll
    for (int fn = 0; fn < 2; ++fn)
      #pragma unroll
      for (int kh = 0; kh < 2; ++kh)
        acc[MH * 4 + fm][NH * 2 + fn] =
            __builtin_amdgcn_mfma_f32_16x16x32_bf16(af[fm][kh], bq[fn][kh],
                                                    acc[MH * 4 + fm][NH * 2 + fn], 0, 0, 0);
  __builtin_amdgcn_s_setprio(0);
}

template<int BUF, int HALF>
__device__ __forceinline__ void stA(const unsigned short* xb, char* ldsc, int kt,
                                    int gArow0, int gArow1, int gcol, int lo0, int lo1) {
  const unsigned short* s0 = xb + (size_t)(gArow0 + HALF * 64) * K_DIM + kt * 64 + gcol;
  const unsigned short* s1 = xb + (size_t)(gArow1 + HALF * 64) * K_DIM + kt * 64 + gcol;
  GLOAD_LDS16(s0, ldsc + (BUF * 2 + HALF) * 16384 + lo0);
  GLOAD_LDS16(s1, ldsc + (BUF * 2 + HALF) * 16384 + lo1);
}

template<int BUF, int HALF>
__device__ __forceinline__ void stB(const unsigned short* W, char* ldsc, int kt,
                                    int gBrow0, int gBrow1, int gcol, int lo0, int lo1) {
  const unsigned short* s0 = W + (size_t)(gBrow0 + HALF * 32) * K_DIM + kt * 64 + gcol;
  const unsigned short* s1 = W + (size_t)(gBrow1 + HALF * 32) * K_DIM + kt * 64 + gcol;
  GLOAD_LDS16(s0, ldsc + 65536 + (BUF * 2 + HALF) * 16384 + lo0);
  GLOAD_LDS16(s1, ldsc + 65536 + (BUF * 2 + HALF) * 16384 + lo1);
}

__global__ __launch_bounds__(512) void gemm8_kernel(const unsigned short* __restrict__ xb,
                                                    const unsigned short* __restrict__ W,
                                                    float* __restrict__ y) {
  extern __shared__ __align__(16) char ldsc[];   // 131072 bytes

  // XCD-aware bijective swizzle: 512 blocks, 8 XCDs, 64 per XCD
  int bid = blockIdx.x;
  int swz = (bid & 7) * 64 + (bid >> 3);
  int brow = (swz >> 4) * 256;   // 32 row-tiles
  int bcol = (swz & 15) * 256;   // 16 col-tiles

  int tid  = threadIdx.x;
  int lane = tid & 63;
  int wid  = tid >> 6;
  int wr = wid >> 2;     // 0..1
  int wc = wid & 3;      // 0..3

  // ds_read addressing (within a 16 KiB half-slot)
  int kOff[2], aRow[4], bRow[2];
  #pragma unroll
  for (int kh = 0; kh < 2; ++kh) kOff[kh] = ((kh * 4 + (lane >> 4)) ^ (lane & 7)) << 4;
  #pragma unroll
  for (int fm = 0; fm < 4; ++fm) aRow[fm] = (wr * 64 + fm * 16 + (lane & 15)) << 7;
  #pragma unroll
  for (int fn = 0; fn < 2; ++fn) bRow[fn] = (wc * 32 + fn * 16 + (lane & 15)) << 7;

  // staging addressing
  int q0 = wid * 16 + (lane >> 3);           // local row, load 0
  int q1 = q0 + 8;                           // local row, load 1
  int lo0 = wid * 2048 + lane * 16;
  int lo1 = lo0 + 1024;
  int gcol = ((lane & 7) ^ (lane >> 3)) << 3;   // pre-swizzled source chunk
  int gArow0 = brow + (q0 >> 6) * 128 + (q0 & 63);
  int gArow1 = brow + (q1 >> 6) * 128 + (q1 & 63);
  int gBrow0 = bcol + (q0 >> 5) * 64 + (q0 & 31);
  int gBrow1 = bcol + (q1 >> 5) * 64 + (q1 & 31);

  f32x4 acc[8][4];
  #pragma unroll
  for (int m = 0; m < 8; ++m)
    #pragma unroll
    for (int n = 0; n < 4; ++n)
      acc[m][n] = (f32x4){0.f, 0.f, 0.f, 0.f};

  bf16x8 af[4][2], bq[2][2];

  // prologue: K-tile 0 fully + A0/B1 of K-tile 1
  stA<0,0>(xb, ldsc, 0, gArow0, gArow1, gcol, lo0, lo1);
  stB<0,1>(W,  ldsc, 0, gBrow0, gBrow1, gcol, lo0, lo1);
  stA<0,1>(xb, ldsc, 0, gArow0, gArow1, gcol, lo0, lo1);
  stB<0,0>(W,  ldsc, 0, gBrow0, gBrow1, gcol, lo0, lo1);
  stA<1,0>(xb, ldsc, 1, gArow0, gArow1, gcol, lo0, lo1);
  stB<1,1>(W,  ldsc, 1, gBrow0, gBrow1, gcol, lo0, lo1);
  WAIT_VM4(); BAR();

  #pragma unroll 1
  for (int i = 0; i < NKT / 2; ++i) {
    int t1 = 2 * i + 1;
    int t2 = 2 * i + 2; if (t2 > NKT - 1) t2 = NKT - 1;
    int t3 = 2 * i + 3; if (t3 > NKT - 1) t3 = NKT - 1;

    // ph1: quadrant (0,0) of buf0
    lda<0,0>(ldsc, aRow, kOff, af);
    ldb<0,0>(ldsc, bRow, kOff, bq);
    stA<1,1>(xb, ldsc, t1, gArow0, gArow1, gcol, lo0, lo1);
    BAR(); WAIT_LGKM0();
    mm<0,0>(af, bq, acc);
    BAR();
    // ph2: (0,1)
    ldb<0,1>(ldsc, bRow, kOff, bq);
    stB<1,0>(W, ldsc, t1, gBrow0, gBrow1, gcol, lo0, lo1);
    BAR(); WAIT_LGKM0();
    mm<0,1>(af, bq, acc);
    BAR();
    // ph3: (1,1)
    lda<0,1>(ldsc, aRow, kOff, af);
    stA<0,0>(xb, ldsc, t2, gArow0, gArow1, gcol, lo0, lo1);
    BAR(); WAIT_LGKM0();
    mm<1,1>(af, bq, acc);
    BAR();
    // ph4: (1,0)  + vmcnt gate for buf1
    ldb<0,0>(ldsc, bRow, kOff, bq);
    stB<0,1>(W, ldsc, t2, gBrow0, gBrow1, gcol, lo0, lo1);
    WAIT_VM4(); BAR(); WAIT_LGKM0();
    mm<1,0>(af, bq, acc);
    BAR();
    // ph5: quadrant (0,0) of buf1
    lda<1,0>(ldsc, aRow, kOff, af);
    ldb<1,0>(ldsc, bRow, kOff, bq);
    stA<0,1>(xb, ldsc, t2, gArow0, gArow1, gcol, lo0, lo1);
    BAR(); WAIT_LGKM0();
    mm<0,0>(af, bq, acc);
    BAR();
    // ph6: (0,1)
    ldb<1,1>(ldsc, bRow, kOff, bq);
    stB<0,0>(W, ldsc, t2, gBrow0, gBrow1, gcol, lo0, lo1);
    BAR(); WAIT_LGKM0();
    mm<0,1>(af, bq, acc);
    BAR();
    // ph7: (1,1)
    lda<1,1>(ldsc, aRow, kOff, af);
    stA<1,0>(xb, ldsc, t3, gArow0, gArow1, gcol, lo0, lo1);
    BAR(); WAIT_LGKM0();
    mm<1,1>(af, bq, acc);
    BAR();
    // ph8: (1,0) + vmcnt gate for buf0
    ldb<1,0>(ldsc, bRow, kOff, bq);
    stB<1,1>(W, ldsc, t3, gBrow0, gBrow1, gcol, lo0, lo1);
    WAIT_VM4(); BAR(); WAIT_LGKM0();
    mm<1,0>(af, bq, acc);
    BAR();
  }

  WAIT_VM0(); BAR();

  // epilogue: C/D layout col=lane&15, row=(lane>>4)*4+j
  #pragma unroll
  for (int am = 0; am < 8; ++am) {
    #pragma unroll
    for (int an = 0; an < 4; ++an) {
      int row0 = brow + wr * 128 + am * 16 + (lane >> 4) * 4;
      int col  = bcol + wc * 64 + an * 16 + (lane & 15);
      #pragma unroll
      for (int j = 0; j < 4; ++j)
        y[(size_t)(row0 + j) * M_W + col] = acc[am][an][j];
    }
  }
}

extern "C" void kernel_launch(void* const* d_in, const int* in_sizes, int n_in,
                              void* d_out, int out_size, void* d_ws, size_t ws_size,
                              hipStream_t stream) {
  const float* inp     = (const float*)d_in[0];
  const int*   trellis = (const int*)d_in[1];
  const float* tlut    = (const float*)d_in[2];
  float* y = (float*)d_out;

  unsigned short* xb = (unsigned short*)d_ws;                                      // 64 MiB
  unsigned short* Wd = (unsigned short*)((char*)d_ws + (size_t)M_X * K_DIM * 2);   // 32 MiB

  (void)hipFuncSetAttribute((const void*)gemm8_kernel,
                            hipFuncAttributeMaxDynamicSharedMemorySize, 131072);

  cvt_kernel<<<M_X * K_DIM / 8 / 256, 256, 0, stream>>>(inp, xb);
  decode_kernel<<<NT_T * TSTEPS / 256, 256, 0, stream>>>(trellis, tlut, Wd);
  gemm8_kernel<<<dim3(512), dim3(512), 131072, stream>>>(xb, Wd, y);
}

// Round 3
// 280.098 us; speedup vs baseline: 1.5853x; 1.0061x over previous
//
#include <hip/hip_runtime.h>
#include <hip/hip_bf16.h>

#define AS1 __attribute__((address_space(1)))
#define AS3 __attribute__((address_space(3)))

typedef __bf16 bf16x8 __attribute__((ext_vector_type(8)));
typedef float f32x4 __attribute__((ext_vector_type(4)));

#define GLOAD_LDS16(gptr, lptr) \
  __builtin_amdgcn_global_load_lds((AS1 void*)(gptr), (AS3 void*)(lptr), 16, 0, 0)

#define M_W   4096   // output features (rows of W)
#define K_DIM 4096
#define M_X   8192   // batch*seq
#define NT_T  65536
#define TSTEPS 128
#define NKT   (K_DIM/64)   // 64 K-tiles of 64

#define BAR()        __builtin_amdgcn_s_barrier()
#define WAIT_LGKM0() asm volatile("s_waitcnt lgkmcnt(0)" ::: "memory")
#define WAIT_LGKM8() asm volatile("s_waitcnt lgkmcnt(8)" ::: "memory")
#define WAIT_VM4()   asm volatile("s_waitcnt vmcnt(4)" ::: "memory")
#define WAIT_VM0()   asm volatile("s_waitcnt vmcnt(0)" ::: "memory")

__device__ __forceinline__ unsigned short f2bf(float f) {
  unsigned int u = __float_as_uint(f);
  unsigned int r = (u + 0x7FFFu + ((u >> 16) & 1u)) >> 16;
  return (unsigned short)r;
}

// ---------------- x fp32 -> bf16 ----------------
__global__ void cvt_kernel(const float* __restrict__ x, unsigned short* __restrict__ xb) {
  int idx = blockIdx.x * blockDim.x + threadIdx.x;
  const float4* p = reinterpret_cast<const float4*>(x) + (size_t)idx * 2;
  float4 u = p[0];
  float4 v = p[1];
  uint4 o;
  o.x = (unsigned)f2bf(u.x) | ((unsigned)f2bf(u.y) << 16);
  o.y = (unsigned)f2bf(u.z) | ((unsigned)f2bf(u.w) << 16);
  o.z = (unsigned)f2bf(v.x) | ((unsigned)f2bf(v.y) << 16);
  o.w = (unsigned)f2bf(v.z) | ((unsigned)f2bf(v.w) << 16);
  reinterpret_cast<uint4*>(xb)[idx] = o;
}

// ---------------- trellis decode -> W bf16 [4096][4096] ----------------
__global__ void decode_kernel(const int* __restrict__ trellis,
                              const float* __restrict__ tlut,
                              unsigned short* __restrict__ W) {
  int idx = blockIdx.x * blockDim.x + threadIdx.x;   // t*128 + s
  int t = idx >> 7;
  int s = idx & 127;
  const unsigned int* tr = reinterpret_cast<const unsigned int*>(trellis) + t * 32;
  int w0  = s >> 2;
  int off = (s & 3) * 4;
  unsigned int a = tr[w0] & 0xFFFFu;
  unsigned int state;
  if (off == 0) {
    state = a;
  } else {
    unsigned int b = tr[(w0 + 1) & 31] & 0xFFFFu;
    state = ((a << off) | (b >> (16 - off))) & 0xFFFFu;
  }
  unsigned int code = state & 0x1FFu;
  float2 v = reinterpret_cast<const float2*>(tlut)[code];
  int i = t >> 8;
  int j = t & 255;
  int flat = s * 2;
  int r = flat >> 4;
  int c = flat & 15;
  unsigned int packed = (unsigned)f2bf(v.x) | ((unsigned)f2bf(v.y) << 16);
  size_t o = (size_t)(i * 16 + r) * K_DIM + (j * 16 + c);
  *reinterpret_cast<unsigned int*>(W + o) = packed;
}

// ---------------- 256x256 8-phase bf16 GEMM ----------------
// y[8192,4096] = xb[8192,4096] * W[4096,4096]^T
// LDS slots (bytes): A(buf,half) = (buf*2+half)*16384 ; B(buf,half) = 65536 + (buf*2+half)*16384
// Half-tile layout: 128 local rows x 64 cols bf16, row stride 128 B, 16B chunks XOR-swizzled:
//   LDS(la, c16) holds global chunk (c16 ^ (la&7)) of row(la).

template<int BUF, int MH>
__device__ __forceinline__ void lda(const char* ldsc, const int* aRow, const int* kOff,
                                    bf16x8 af[4][2]) {
  const char* base = ldsc + (BUF * 2 + MH) * 16384;
  #pragma unroll
  for (int fm = 0; fm < 4; ++fm)
    #pragma unroll
    for (int kh = 0; kh < 2; ++kh)
      af[fm][kh] = *(const bf16x8*)(base + aRow[fm] + kOff[kh]);
}

template<int BUF, int NH>
__device__ __forceinline__ void ldb(const char* ldsc, const int* bRow, const int* kOff,
                                    bf16x8 bq[2][2]) {
  const char* base = ldsc + 65536 + (BUF * 2 + NH) * 16384;
  #pragma unroll
  for (int fn = 0; fn < 2; ++fn)
    #pragma unroll
    for (int kh = 0; kh < 2; ++kh)
      bq[fn][kh] = *(const bf16x8*)(base + bRow[fn] + kOff[kh]);
}

template<int MH, int NH>
__device__ __forceinline__ void mm(bf16x8 af[4][2], bf16x8 bq[2][2], f32x4 acc[8][4]) {
  __builtin_amdgcn_s_setprio(1);
  #pragma unroll
  for (int fm = 0; fm < 4; ++fm)
    #pragma unroll
    for (int fn = 0; fn < 2; ++fn)
      #pragma unroll
      for (int kh = 0; kh < 2; ++kh)
        acc[MH * 4 + fm][NH * 2 + fn] =
            __builtin_amdgcn_mfma_f32_16x16x32_bf16(af[fm][kh], bq[fn][kh],
                                                    acc[MH * 4 + fm][NH * 2 + fn], 0, 0, 0);
  __builtin_amdgcn_s_setprio(0);
}

template<int BUF, int HALF>
__device__ __forceinline__ void stA(const unsigned short* xb, char* ldsc, int kt,
                                    int gArow0, int gArow1, int gcol, int lo0, int lo1) {
  const unsigned short* s0 = xb + (size_t)(gArow0 + HALF * 64) * K_DIM + kt * 64 + gcol;
  const unsigned short* s1 = xb + (size_t)(gArow1 + HALF * 64) * K_DIM + kt * 64 + gcol;
  GLOAD_LDS16(s0, ldsc + (BUF * 2 + HALF) * 16384 + lo0);
  GLOAD_LDS16(s1, ldsc + (BUF * 2 + HALF) * 16384 + lo1);
}

template<int BUF, int HALF>
__device__ __forceinline__ void stB(const unsigned short* W, char* ldsc, int kt,
                                    int gBrow0, int gBrow1, int gcol, int lo0, int lo1) {
  const unsigned short* s0 = W + (size_t)(gBrow0 + HALF * 32) * K_DIM + kt * 64 + gcol;
  const unsigned short* s1 = W + (size_t)(gBrow1 + HALF * 32) * K_DIM + kt * 64 + gcol;
  GLOAD_LDS16(s0, ldsc + 65536 + (BUF * 2 + HALF) * 16384 + lo0);
  GLOAD_LDS16(s1, ldsc + 65536 + (BUF * 2 + HALF) * 16384 + lo1);
}

__global__ __launch_bounds__(512) void gemm8_kernel(const unsigned short* __restrict__ xb,
                                                    const unsigned short* __restrict__ W,
                                                    float* __restrict__ y) {
  extern __shared__ __align__(16) char ldsc[];   // 131072 bytes

  // XCD-aware bijective swizzle: 512 blocks, 8 XCDs, 64 per XCD
  int bid = blockIdx.x;
  int swz = (bid & 7) * 64 + (bid >> 3);
  int brow = (swz >> 4) * 256;   // 32 row-tiles
  int bcol = (swz & 15) * 256;   // 16 col-tiles

  int tid  = threadIdx.x;
  int lane = tid & 63;
  int wid  = tid >> 6;
  int wr = wid >> 2;     // 0..1
  int wc = wid & 3;      // 0..3

  // ds_read addressing (within a 16 KiB half-slot)
  int kOff[2], aRow[4], bRow[2];
  #pragma unroll
  for (int kh = 0; kh < 2; ++kh) kOff[kh] = ((kh * 4 + (lane >> 4)) ^ (lane & 7)) << 4;
  #pragma unroll
  for (int fm = 0; fm < 4; ++fm) aRow[fm] = (wr * 64 + fm * 16 + (lane & 15)) << 7;
  #pragma unroll
  for (int fn = 0; fn < 2; ++fn) bRow[fn] = (wc * 32 + fn * 16 + (lane & 15)) << 7;

  // staging addressing
  int q0 = wid * 16 + (lane >> 3);           // local row, load 0
  int q1 = q0 + 8;                           // local row, load 1
  int lo0 = wid * 2048 + lane * 16;
  int lo1 = lo0 + 1024;
  int gcol = ((lane & 7) ^ (lane >> 3)) << 3;   // pre-swizzled source chunk
  int gArow0 = brow + (q0 >> 6) * 128 + (q0 & 63);
  int gArow1 = brow + (q1 >> 6) * 128 + (q1 & 63);
  int gBrow0 = bcol + (q0 >> 5) * 64 + (q0 & 31);
  int gBrow1 = bcol + (q1 >> 5) * 64 + (q1 & 31);

  f32x4 acc[8][4];
  #pragma unroll
  for (int m = 0; m < 8; ++m)
    #pragma unroll
    for (int n = 0; n < 4; ++n)
      acc[m][n] = (f32x4){0.f, 0.f, 0.f, 0.f};

  bf16x8 af[4][2];
  bf16x8 bq[2][2][2];    // [NH][fn][kh] — all B fragments of current K-tile

  // prologue: K-tile 0 fully + A0/B1 of K-tile 1
  stA<0,0>(xb, ldsc, 0, gArow0, gArow1, gcol, lo0, lo1);
  stB<0,1>(W,  ldsc, 0, gBrow0, gBrow1, gcol, lo0, lo1);
  stA<0,1>(xb, ldsc, 0, gArow0, gArow1, gcol, lo0, lo1);
  stB<0,0>(W,  ldsc, 0, gBrow0, gBrow1, gcol, lo0, lo1);
  stA<1,0>(xb, ldsc, 1, gArow0, gArow1, gcol, lo0, lo1);
  stB<1,1>(W,  ldsc, 1, gBrow0, gBrow1, gcol, lo0, lo1);
  WAIT_VM4(); BAR();

  #pragma unroll 1
  for (int i = 0; i < NKT / 2; ++i) {
    int t1 = 2 * i + 1;
    int t2 = 2 * i + 2; if (t2 > NKT - 1) t2 = NKT - 1;
    int t3 = 2 * i + 3; if (t3 > NKT - 1) t3 = NKT - 1;

    // ph1: quadrant (0,0) of buf0; load all NH=0 B frags
    lda<0,0>(ldsc, aRow, kOff, af);
    ldb<0,0>(ldsc, bRow, kOff, bq[0]);
    stA<1,1>(xb, ldsc, t1, gArow0, gArow1, gcol, lo0, lo1);
    WAIT_LGKM8(); BAR(); WAIT_LGKM0();
    mm<0,0>(af, bq[0], acc);
    BAR();
    // ph2: (0,1); load all NH=1 B frags
    ldb<0,1>(ldsc, bRow, kOff, bq[1]);
    stB<1,0>(W, ldsc, t1, gBrow0, gBrow1, gcol, lo0, lo1);
    BAR(); WAIT_LGKM0();
    mm<0,1>(af, bq[1], acc);
    BAR();
    // ph3: (1,1)
    lda<0,1>(ldsc, aRow, kOff, af);
    stA<0,0>(xb, ldsc, t2, gArow0, gArow1, gcol, lo0, lo1);
    BAR(); WAIT_LGKM0();
    mm<1,1>(af, bq[1], acc);
    BAR();
    // ph4: (1,0) — B frags held in regs; vmcnt gate for buf1
    stB<0,1>(W, ldsc, t2, gBrow0, gBrow1, gcol, lo0, lo1);
    WAIT_VM4(); BAR();
    mm<1,0>(af, bq[0], acc);
    BAR();
    // ph5: quadrant (0,0) of buf1
    lda<1,0>(ldsc, aRow, kOff, af);
    ldb<1,0>(ldsc, bRow, kOff, bq[0]);
    stA<0,1>(xb, ldsc, t2, gArow0, gArow1, gcol, lo0, lo1);
    WAIT_LGKM8(); BAR(); WAIT_LGKM0();
    mm<0,0>(af, bq[0], acc);
    BAR();
    // ph6: (0,1)
    ldb<1,1>(ldsc, bRow, kOff, bq[1]);
    stB<0,0>(W, ldsc, t2, gBrow0, gBrow1, gcol, lo0, lo1);
    BAR(); WAIT_LGKM0();
    mm<0,1>(af, bq[1], acc);
    BAR();
    // ph7: (1,1)
    lda<1,1>(ldsc, aRow, kOff, af);
    stA<1,0>(xb, ldsc, t3, gArow0, gArow1, gcol, lo0, lo1);
    BAR(); WAIT_LGKM0();
    mm<1,1>(af, bq[1], acc);
    BAR();
    // ph8: (1,0) — B frags held in regs; vmcnt gate for buf0
    stB<1,1>(W, ldsc, t3, gBrow0, gBrow1, gcol, lo0, lo1);
    WAIT_VM4(); BAR();
    mm<1,0>(af, bq[0], acc);
    BAR();
  }

  WAIT_VM0(); BAR();

  // epilogue: C/D layout col=lane&15, row=(lane>>4)*4+j
  #pragma unroll
  for (int am = 0; am < 8; ++am) {
    #pragma unroll
    for (int an = 0; an < 4; ++an) {
      int row0 = brow + wr * 128 + am * 16 + (lane >> 4) * 4;
      int col  = bcol + wc * 64 + an * 16 + (lane & 15);
      #pragma unroll
      for (int j = 0; j < 4; ++j)
        y[(size_t)(row0 + j) * M_W + col] = acc[am][an][j];
    }
  }
}

extern "C" void kernel_launch(void* const* d_in, const int* in_sizes, int n_in,
                              void* d_out, int out_size, void* d_ws, size_t ws_size,
                              hipStream_t stream) {
  const float* inp     = (const float*)d_in[0];
  const int*   trellis = (const int*)d_in[1];
  const float* tlut    = (const float*)d_in[2];
  float* y = (float*)d_out;

  unsigned short* xb = (unsigned short*)d_ws;                                      // 64 MiB
  unsigned short* Wd = (unsigned short*)((char*)d_ws + (size_t)M_X * K_DIM * 2);   // 32 MiB

  (void)hipFuncSetAttribute((const void*)gemm8_kernel,
                            hipFuncAttributeMaxDynamicSharedMemorySize, 131072);

  cvt_kernel<<<M_X * K_DIM / 8 / 256, 256, 0, stream>>>(inp, xb);
  decode_kernel<<<NT_T * TSTEPS / 256, 256, 0, stream>>>(trellis, tlut, Wd);
  gemm8_kernel<<<dim3(512), dim3(512), 131072, stream>>>(xb, Wd, y);
}